// Round 1
// 313.779 us; speedup vs baseline: 1.0361x; 1.0361x over previous
//
#include <hip/hip_runtime.h>
#include <math.h>

typedef __bf16 bf16_t;
typedef __bf16 bf16x8 __attribute__((ext_vector_type(8)));
typedef float  f32x4  __attribute__((ext_vector_type(4)));
typedef float  f32x16 __attribute__((ext_vector_type(16)));
typedef unsigned int u32;
typedef u32 u32x4 __attribute__((ext_vector_type(4)));

#define FRAME 2048
#define NOUT  1580

#define A_STRIDE 2120            // bf16 elements per phase copy (offset 4240B = 16 mod 128: bank-uniform)
#define P_STRIDE 2304            // partial row floats: 2048 + 4*(2048/32), keeps float4 alignment
#define B_OFF_BYTES 36864        // = 4*P_STRIDE*4 (partial overlay region end)
#define DBUF_OFF_BYTES 36864     // dbuf overlays arrB
#define SARR_OFF_BYTES 45056
#define WTOT_OFF_BYTES 53264
#define SMEM_BYTES 53280         // ~53.3KB -> 3 blocks/CU

__global__ __launch_bounds__(256, 3) void yingram_kernel(
    const float* __restrict__ x, float* __restrict__ out,
    const int4* __restrict__ tbl, int use_tbl)
{
    __shared__ alignas(16) char smem[SMEM_BYTES];
    bf16_t* arrA    = (bf16_t*)smem;                      // [8][A_STRIDE]
    char*   arrBb   = smem + B_OFF_BYTES;                 // phys slots: 8*(B + (B>>3)) bf16
    float*  partial = (float*)smem;                       // [4][P_STRIDE] overlay
    float*  dbuf    = (float*)(smem + DBUF_OFF_BYTES);    // [2048] overlay on arrB
    float*  s_arr   = (float*)(smem + SARR_OFF_BYTES);    // [2049]
    float*  wtot    = (float*)(smem + WTOT_OFF_BYTES);    // [4]

    const int tid  = threadIdx.x;
    const int lane = tid & 63;
    const int w    = tid >> 6;
    const int q    = lane >> 5;
    const int col  = lane & 31;
    const float* xp = x + (size_t)blockIdx.x * FRAME;

    // ---- targeted zeroing of never-staged chunks (disjoint from staging: no extra barrier) ----
    if (tid < 64) {
        int sel = tid & 7;
        int c = (sel < 3) ? sel : sel + 257;              // {0,1,2,260..264}
        u32x4 z = {0u,0u,0u,0u};
        *(u32x4*)(arrA + (tid >> 3) * A_STRIDE + 8 * c) = z;
    } else if (tid < 191) {
        int B = tid + 193;                                // logical chunks 257..383
        u32x4 z = {0u,0u,0u,0u};
        *(u32x4*)(arrBb + 16 * (B + (B >> 3))) = z;
    }

    // ---- window load: xt[8tid-8 .. 8tid+7] ----
    f32x4 f0 = {0,0,0,0}, f1 = {0,0,0,0}, f2, f3;
    const f32x4* xv4 = (const f32x4*)(xp + 8 * tid - 8);
    if (tid != 0) { f0 = xv4[0]; f1 = xv4[1]; }
    f2 = xv4[2]; f3 = xv4[3];

    float xf[16];
    #pragma unroll
    for (int i = 0; i < 4; ++i) {
        xf[i] = f0[i]; xf[4+i] = f1[i]; xf[8+i] = f2[i]; xf[12+i] = f3[i];
    }
    // pack to bf16 dwords: W[j] = xb[2j] | xb[2j+1]<<16
    u32 W[8];
    #pragma unroll
    for (int j = 0; j < 8; ++j) {
        union { bf16_t h[2]; u32 u; } cv;
        cv.h[0] = (bf16_t)xf[2*j];
        cv.h[1] = (bf16_t)xf[2*j+1];
        W[j] = cv.u;
    }

    // ---- staging: 8 phase copies (A) + padded B copy, all b128 writes ----
    u32x4 D7;
    #pragma unroll
    for (int p = 0; p < 8; ++p) {
        int a = p >> 1;
        u32x4 D;
        if ((p & 1) == 0) {
            D[0] = W[a]; D[1] = W[a+1]; D[2] = W[a+2]; D[3] = W[a+3];
        } else {
            #pragma unroll
            for (int i = 0; i < 4; ++i)
                D[i] = (W[a+i] >> 16) | (W[a+i+1] << 16);
        }
        *(u32x4*)(arrA + p * A_STRIDE + 8 * (tid + 3)) = D;
        if (p == 7) D7 = D;
    }
    *(u32x4*)(arrBb + 16 * (tid + (tid >> 3))) = D7;      // logical chunk tid = window[7..14]

    if (tid == 255) {
        // A chunk 259 (tail): elements xb[8+p+j], zero beyond window
        #pragma unroll
        for (int p = 0; p < 8; ++p) {
            int a = p >> 1;
            u32x4 D;
            #pragma unroll
            for (int i = 0; i < 4; ++i) {
                int lo = 4 + a + i;
                if ((p & 1) == 0) {
                    D[i] = (lo <= 7) ? W[lo] : 0u;
                } else {
                    u32 x0 = (lo <= 7) ? (W[lo] >> 16) : 0u;
                    u32 x1 = (lo + 1 <= 7) ? (W[lo+1] << 16) : 0u;
                    D[i] = x0 | x1;
                }
            }
            *(u32x4*)(arrA + p * A_STRIDE + 8 * 259) = D;
        }
        u32x4 Db = { W[7] >> 16, 0u, 0u, 0u };            // B chunk 256 = [x2047, 0..]
        *(u32x4*)(arrBb + 16 * (256 + (256 >> 3))) = Db;
    }

    // ---- energy scan part 1 (own elements = xf[8..15]) ----
    float sq[8], pe[8];
    {
        float run = 0.f;
        #pragma unroll
        for (int e = 0; e < 8; ++e) {
            float v = xf[8 + e];
            sq[e] = v * v; run += sq[e]; pe[e] = run;
        }
    }
    float tsum = pe[7];
    float sc = tsum;
    #pragma unroll
    for (int off = 1; off < 64; off <<= 1) {
        float o = __shfl_up(sc, off, 64);
        if (lane >= off) sc += o;
    }
    if (lane == 63) wtot[w] = sc;
    float thr_off = sc - tsum;

    __syncthreads();   // staging + wtot complete

    // ---- energy scan part 2: exclusive prefix -> s_arr ----
    {
        float b0 = wtot[0], b1 = wtot[1], b2 = wtot[2];
        float base = (w > 0 ? b0 : 0.f) + (w > 1 ? b1 : 0.f) + (w > 2 ? b2 : 0.f) + thr_off;
        f32x4 sA, sB;
        #pragma unroll
        for (int i = 0; i < 4; ++i) {
            sA[i] = base + pe[i]   - sq[i];
            sB[i] = base + pe[4+i] - sq[4+i];
        }
        *(f32x4*)(s_arr + 8 * tid)     = sA;
        *(f32x4*)(s_arr + 8 * tid + 4) = sB;
        if (tid == 255) s_arr[2048] = base + pe[7];
    }

    // ---- MFMA K-loop: A-fragment register FIFO removes the b1 re-read.
    //      Identity: old acc1(i) = A(i)*B(i+1024elem) == A(i-16)*B(i) at iter i+16
    //      (b1 offset 1152 phys == 16 iters * 72 phys). 2 reads -> 2 MFMAs in the
    //      dual window; per-block K-loop ds_read_b128 330 -> 260. Bit-identical
    //      accumulation order per acc. Static trip counts -> full unroll/pipelining.
    const bf16_t* aPtr = arrA + (col & 7) * A_STRIDE + (col & ~7) + 8 * q + 16 * w;
    int B0 = 2 * w + q + 4 * col;
    const bf16_t* bPtr = (const bf16_t*)arrBb + 8 * (B0 + (B0 >> 3));
    f32x16 acc0, acc1;
    #pragma unroll
    for (int v = 0; v < 16; ++v) { acc0[v] = 0.f; acc1[v] = 0.f; }

    bf16x8 fifo[16];
    #pragma unroll
    for (int i = 0; i < 16; ++i) {                        // global i = 0..15: fill FIFO
        bf16x8 av = *(const bf16x8*)aPtr;
        bf16x8 bv = *(const bf16x8*)bPtr;
        acc0 = __builtin_amdgcn_mfma_f32_32x32x16_bf16(av, bv, acc0, 0, 0, 0);
        fifo[i] = av;
        aPtr += 64; bPtr += 72;
    }
    #pragma unroll
    for (int i = 0; i < 16; ++i) {                        // global i = 16..31: dual
        bf16x8 av = *(const bf16x8*)aPtr;
        bf16x8 bv = *(const bf16x8*)bPtr;
        acc0 = __builtin_amdgcn_mfma_f32_32x32x16_bf16(av, bv, acc0, 0, 0, 0);
        acc1 = __builtin_amdgcn_mfma_f32_32x32x16_bf16(fifo[i], bv, acc1, 0, 0, 0);
        fifo[i] = av;                                     // fifo[0] <- A(16) for the w==0 tail
        aPtr += 64; bPtr += 72;
    }
    if (w < 2) {                                          // global i = 32 (k = 128/129)
        bf16x8 av = *(const bf16x8*)aPtr;
        bf16x8 bv = *(const bf16x8*)bPtr;
        acc0 = __builtin_amdgcn_mfma_f32_32x32x16_bf16(av, bv, acc0, 0, 0, 0);
        if (w == 0)
            acc1 = __builtin_amdgcn_mfma_f32_32x32x16_bf16(fifo[0], bv, acc1, 0, 0, 0);
    }

    __syncthreads();   // all waves done reading arrA/arrB

    // ---- partial writes: float4 groups (reg j=3..0 -> descending lags) ----
    float* prow = partial + w * P_STRIDE;
    #pragma unroll
    for (int g = 0; g < 4; ++g) {
        int L0 = 28 + 32 * col - 8 * g - 4 * q;
        int i0 = L0 + 4 * (L0 >> 5);
        f32x4 v0 = { acc0[4*g+3], acc0[4*g+2], acc0[4*g+1], acc0[4*g] };
        *(f32x4*)(prow + i0) = v0;
        int L1 = L0 + 1024;
        int i1 = L1 + 4 * (L1 >> 5);
        f32x4 v1 = { acc1[4*g+3], acc1[4*g+2], acc1[4*g+1], acc1[4*g] };
        *(f32x4*)(prow + i1) = v1;
    }
    __syncthreads();

    // ---- reduce partials, d_raw, scan part 1 ----
    const int tb = 8 * tid;
    const int ip = tb + 4 * (tb >> 5);
    f32x4 rA = {0,0,0,0}, rB = {0,0,0,0};
    #pragma unroll
    for (int ww = 0; ww < 4; ++ww) {
        rA += *(f32x4*)(partial + ww * P_STRIDE + ip);
        rB += *(f32x4*)(partial + ww * P_STRIDE + ip + 4);
    }
    const float sW = s_arr[2048];
    f32x4 s0v = *(f32x4*)(s_arr + tb);
    f32x4 s1v = *(f32x4*)(s_arr + tb + 4);
    f32x4 q0  = *(f32x4*)(s_arr + 2040 - tb);
    f32x4 q1  = *(f32x4*)(s_arr + 2044 - tb);
    float e0  = s_arr[2048 - tb];

    float dr[8], pe2[8];
    {
        float term1[8] = { e0, q1[3], q1[2], q1[1], q1[0], q0[3], q0[2], q0[1] };
        float rr[8] = { rA[0],rA[1],rA[2],rA[3], rB[0],rB[1],rB[2],rB[3] };
        float ss[8] = { s0v[0],s0v[1],s0v[2],s0v[3], s1v[0],s1v[1],s1v[2],s1v[3] };
        #pragma unroll
        for (int e = 0; e < 8; ++e)
            dr[e] = term1[e] + sW - ss[e] - 2.f * rr[e];
        if (tid == 0) dr[0] = 0.f;
        float run = 0.f;
        #pragma unroll
        for (int e = 0; e < 8; ++e) { run += dr[e]; pe2[e] = run; }
    }
    float tsum2 = pe2[7];
    float sc2 = tsum2;
    #pragma unroll
    for (int off = 1; off < 64; off <<= 1) {
        float o = __shfl_up(sc2, off, 64);
        if (lane >= off) sc2 += o;
    }
    if (lane == 63) wtot[w] = sc2;
    float thr2 = sc2 - tsum2;
    __syncthreads();

    // ---- scan part 2: normalize -> dbuf ----
    {
        float b0 = wtot[0], b1 = wtot[1], b2 = wtot[2];
        float base = (w > 0 ? b0 : 0.f) + (w > 1 ? b1 : 0.f) + (w > 2 ? b2 : 0.f) + thr2;
        f32x4 dA, dB;
        #pragma unroll
        for (int i = 0; i < 4; ++i) {
            float cumA = base + pe2[i];
            float cumB = base + pe2[4+i];
            dA[i] = (float)(tb + i)     * dr[i]   / (cumA + 1e-7f);
            dB[i] = (float)(tb + 4 + i) * dr[4+i] / (cumB + 1e-7f);
        }
        *(f32x4*)(dbuf + tb)     = dA;
        *(f32x4*)(dbuf + tb + 4) = dB;
    }
    __syncthreads();

    // ---- gather-interpolate ----
    float* op = out + (size_t)blockIdx.x * NOUT;
    if (use_tbl) {
        for (int m = tid; m < NOUT; m += 256) {
            int4 e = tbl[m];
            float wd = __int_as_float(e.z);
            float df = dbuf[e.x], dc = dbuf[e.y];
            op[m] = wd * (dc - df) + df;
        }
    } else {
        for (int m = tid; m < NOUT; m += 256) {
            double midi = 5.0 + (double)m * 0.05;
            float  mf   = (float)midi;
            double lag64 = 22050.0 / (440.0 * exp2(((double)mf - 69.0) / 12.0));
            float  lag  = (float)lag64;
            float  cf = ceilf(lag), ff = floorf(lag);
            float  dc = dbuf[(int)cf], df = dbuf[(int)ff];
            op[m] = (lag - ff) * (dc - df) / (cf - ff) + df;
        }
    }
}

__global__ void table_kernel(int4* __restrict__ tbl) {
    int m = blockIdx.x * 256 + threadIdx.x;
    if (m >= NOUT) return;
    double midi = 5.0 + (double)m * 0.05;            // mirrors np.arange fp64
    float  mf   = (float)midi;                       // .astype(float32)
    double lag64 = 22050.0 / (440.0 * exp2(((double)mf - 69.0) / 12.0));
    float  lag  = (float)lag64;                      // .astype(float32)
    float  cf = ceilf(lag), ff = floorf(lag);
    float  wd = (cf > ff) ? (lag - ff) / (cf - ff) : 0.f;
    int4 e; e.x = (int)ff; e.y = (int)cf; e.z = __float_as_int(wd); e.w = 0;
    tbl[m] = e;
}

extern "C" void kernel_launch(void* const* d_in, const int* in_sizes, int n_in,
                              void* d_out, int out_size, void* d_ws, size_t ws_size,
                              hipStream_t stream) {
    const float* x = (const float*)d_in[0];
    float* out = (float*)d_out;
    int frames = in_sizes[0] / FRAME;   // 16384
    int use_tbl = (ws_size >= (size_t)NOUT * sizeof(int4)) ? 1 : 0;
    int4* tbl = (int4*)d_ws;
    if (use_tbl)
        table_kernel<<<dim3((NOUT + 255) / 256), dim3(256), 0, stream>>>(tbl);
    yingram_kernel<<<dim3(frames), dim3(256), 0, stream>>>(x, out, tbl, use_tbl);
}

// Round 2
// 309.507 us; speedup vs baseline: 1.0504x; 1.0138x over previous
//
#include <hip/hip_runtime.h>
#include <math.h>

typedef __bf16 bf16_t;
typedef __bf16 bf16x8 __attribute__((ext_vector_type(8)));
typedef float  f32x4  __attribute__((ext_vector_type(4)));
typedef float  f32x16 __attribute__((ext_vector_type(16)));
typedef unsigned int u32;
typedef u32 u32x4 __attribute__((ext_vector_type(4)));

#define FRAME 2048
#define NOUT  1580

#define A_STRIDE 2120            // bf16 elements per phase copy (offset 4240B = 16 mod 128: bank-uniform)
#define PROW 2048                // partial row floats (no pad; XOR-swizzled units)
#define B_OFF_BYTES 33920        // arrB directly after arrA (base mod 128 == 0, same as before)
#define SARR_OFF_BYTES 32768     // phase-2 s_arr (2048 floats, swizzled) overlays arrA tail + arrB
#define SMEM_BYTES 40960         // == 163840/4 exactly -> 4 blocks/CU

// unit-level XOR swizzle: u = float4-unit index within a 2048-float row.
// Spreads stride-128B accesses across all 8 16B slots; bijective on [0,512).
__device__ __forceinline__ int swz(int u) { return u ^ ((u >> 3) & 7); }

__global__ __launch_bounds__(256, 4) void yingram_kernel(
    const float* __restrict__ x, float* __restrict__ out,
    const int4* __restrict__ tbl, int use_tbl)
{
    __shared__ alignas(16) char smem[SMEM_BYTES];
    bf16_t* arrA    = (bf16_t*)smem;                      // [8][A_STRIDE]
    char*   arrBb   = smem + B_OFF_BYTES;                 // phys slots: 16*(B + (B>>3)) bytes, B in [0,384)
    float*  wtot1   = (float*)(smem + B_OFF_BYTES + 128); // arrB pad gap (phys slot 8: B+(B>>3) never == 8)
    float*  partial = (float*)smem;                       // [4][PROW] overlay (phase 2)
    float*  s_arr   = (float*)(smem + SARR_OFF_BYTES);    // [2048] swizzled (phase 2)
    float*  dbuf    = (float*)smem;                       // [2048] overlay on partial row 0 (phase 2b)

    const int tid  = threadIdx.x;
    const int lane = tid & 63;
    const int w    = tid >> 6;
    const int q    = lane >> 5;
    const int col  = lane & 31;
    const float* xp = x + (size_t)blockIdx.x * FRAME;

    // ---- targeted zeroing of never-staged chunks (disjoint from staging: no extra barrier) ----
    if (tid < 64) {
        int sel = tid & 7;
        int c = (sel < 3) ? sel : sel + 257;              // {0,1,2,260..264}
        u32x4 z = {0u,0u,0u,0u};
        *(u32x4*)(arrA + (tid >> 3) * A_STRIDE + 8 * c) = z;
    } else if (tid < 191) {
        int B = tid + 193;                                // logical chunks 257..383
        u32x4 z = {0u,0u,0u,0u};
        *(u32x4*)(arrBb + 16 * (B + (B >> 3))) = z;
    }

    // ---- window load: xt[8tid-8 .. 8tid+7] ----
    f32x4 f0 = {0,0,0,0}, f1 = {0,0,0,0}, f2, f3;
    const f32x4* xv4 = (const f32x4*)(xp + 8 * tid - 8);
    if (tid != 0) { f0 = xv4[0]; f1 = xv4[1]; }
    f2 = xv4[2]; f3 = xv4[3];

    float xf[16];
    #pragma unroll
    for (int i = 0; i < 4; ++i) {
        xf[i] = f0[i]; xf[4+i] = f1[i]; xf[8+i] = f2[i]; xf[12+i] = f3[i];
    }
    // pack to bf16 dwords: W[j] = xb[2j] | xb[2j+1]<<16
    u32 W[8];
    #pragma unroll
    for (int j = 0; j < 8; ++j) {
        union { bf16_t h[2]; u32 u; } cv;
        cv.h[0] = (bf16_t)xf[2*j];
        cv.h[1] = (bf16_t)xf[2*j+1];
        W[j] = cv.u;
    }

    // ---- staging: 8 phase copies (A) + padded B copy, all b128 writes ----
    u32x4 D7;
    #pragma unroll
    for (int p = 0; p < 8; ++p) {
        int a = p >> 1;
        u32x4 D;
        if ((p & 1) == 0) {
            D[0] = W[a]; D[1] = W[a+1]; D[2] = W[a+2]; D[3] = W[a+3];
        } else {
            #pragma unroll
            for (int i = 0; i < 4; ++i)
                D[i] = (W[a+i] >> 16) | (W[a+i+1] << 16);
        }
        *(u32x4*)(arrA + p * A_STRIDE + 8 * (tid + 3)) = D;
        if (p == 7) D7 = D;
    }
    *(u32x4*)(arrBb + 16 * (tid + (tid >> 3))) = D7;      // logical chunk tid = window[7..14]

    if (tid == 255) {
        // A chunk 259 (tail): elements xb[8+p+j], zero beyond window
        #pragma unroll
        for (int p = 0; p < 8; ++p) {
            int a = p >> 1;
            u32x4 D;
            #pragma unroll
            for (int i = 0; i < 4; ++i) {
                int lo = 4 + a + i;
                if ((p & 1) == 0) {
                    D[i] = (lo <= 7) ? W[lo] : 0u;
                } else {
                    u32 x0 = (lo <= 7) ? (W[lo] >> 16) : 0u;
                    u32 x1 = (lo + 1 <= 7) ? (W[lo+1] << 16) : 0u;
                    D[i] = x0 | x1;
                }
            }
            *(u32x4*)(arrA + p * A_STRIDE + 8 * 259) = D;
        }
        u32x4 Db = { W[7] >> 16, 0u, 0u, 0u };            // B chunk 256 = [x2047, 0..]
        *(u32x4*)(arrBb + 16 * (256 + (256 >> 3))) = Db;
    }

    // ---- energy scan part 1 (own elements = xf[8..15]) ----
    float sq[8], pe[8];
    {
        float run = 0.f;
        #pragma unroll
        for (int e = 0; e < 8; ++e) {
            float v = xf[8 + e];
            sq[e] = v * v; run += sq[e]; pe[e] = run;
        }
    }
    float tsum = pe[7];
    float sc = tsum;
    #pragma unroll
    for (int off = 1; off < 64; off <<= 1) {
        float o = __shfl_up(sc, off, 64);
        if (lane >= off) sc += o;
    }
    if (lane == 63) wtot1[w] = sc;
    float thr_off = sc - tsum;

    __syncthreads();   // staging + wtot1 complete

    // ---- energy scan part 2: exclusive prefix kept in REGISTERS (written to LDS after K-loop) ----
    f32x4 sA, sB;
    float sW;
    {
        float b0 = wtot1[0], b1 = wtot1[1], b2 = wtot1[2], b3 = wtot1[3];
        float base = (w > 0 ? b0 : 0.f) + (w > 1 ? b1 : 0.f) + (w > 2 ? b2 : 0.f) + thr_off;
        sW = b0 + b1 + b2 + b3;                           // total energy s[2048]
        #pragma unroll
        for (int i = 0; i < 4; ++i) {
            sA[i] = base + pe[i]   - sq[i];
            sB[i] = base + pe[4+i] - sq[4+i];
        }
    }

    // ---- MFMA K-loop: A-fragment register FIFO removes the b1 re-read. ----
    const bf16_t* aPtr = arrA + (col & 7) * A_STRIDE + (col & ~7) + 8 * q + 16 * w;
    int B0 = 2 * w + q + 4 * col;
    const bf16_t* bPtr = (const bf16_t*)arrBb + 8 * (B0 + (B0 >> 3));
    f32x16 acc0, acc1;
    #pragma unroll
    for (int v = 0; v < 16; ++v) { acc0[v] = 0.f; acc1[v] = 0.f; }

    bf16x8 fifo[16];
    #pragma unroll
    for (int i = 0; i < 16; ++i) {                        // global i = 0..15: fill FIFO
        bf16x8 av = *(const bf16x8*)aPtr;
        bf16x8 bv = *(const bf16x8*)bPtr;
        acc0 = __builtin_amdgcn_mfma_f32_32x32x16_bf16(av, bv, acc0, 0, 0, 0);
        fifo[i] = av;
        aPtr += 64; bPtr += 72;
    }
    #pragma unroll
    for (int i = 0; i < 16; ++i) {                        // global i = 16..31: dual
        bf16x8 av = *(const bf16x8*)aPtr;
        bf16x8 bv = *(const bf16x8*)bPtr;
        acc0 = __builtin_amdgcn_mfma_f32_32x32x16_bf16(av, bv, acc0, 0, 0, 0);
        acc1 = __builtin_amdgcn_mfma_f32_32x32x16_bf16(fifo[i], bv, acc1, 0, 0, 0);
        fifo[i] = av;                                     // fifo[0] <- A(16) for the w==0 tail
        aPtr += 64; bPtr += 72;
    }
    if (w < 2) {                                          // global i = 32 (k = 128/129)
        bf16x8 av = *(const bf16x8*)aPtr;
        bf16x8 bv = *(const bf16x8*)bPtr;
        acc0 = __builtin_amdgcn_mfma_f32_32x32x16_bf16(av, bv, acc0, 0, 0, 0);
        if (w == 0)
            acc1 = __builtin_amdgcn_mfma_f32_32x32x16_bf16(fifo[0], bv, acc1, 0, 0, 0);
    }

    __syncthreads();   // all waves done reading arrA/arrB

    // ---- partial + s_arr writes: swizzled float4 units (reg j=3..0 -> descending lags) ----
    float* prow = partial + w * PROW;
    #pragma unroll
    for (int g = 0; g < 4; ++g) {
        int L0 = 28 + 32 * col - 8 * g - 4 * q;
        f32x4 v0 = { acc0[4*g+3], acc0[4*g+2], acc0[4*g+1], acc0[4*g] };
        *(f32x4*)(prow + (swz(L0 >> 2) << 2)) = v0;
        int L1 = L0 + 1024;
        f32x4 v1 = { acc1[4*g+3], acc1[4*g+2], acc1[4*g+1], acc1[4*g] };
        *(f32x4*)(prow + (swz(L1 >> 2) << 2)) = v1;
    }
    *(f32x4*)(s_arr + (swz(2 * tid) << 2))     = sA;      // s[8tid..8tid+3]
    *(f32x4*)(s_arr + (swz(2 * tid + 1) << 2)) = sB;      // s[8tid+4..8tid+7]
    __syncthreads();

    // ---- reduce partials, d_raw, scan part 1 ----
    const int tb = 8 * tid;
    const int o0 = swz(2 * tid) << 2;
    const int o1 = swz(2 * tid + 1) << 2;
    f32x4 rA = {0,0,0,0}, rB = {0,0,0,0};
    #pragma unroll
    for (int ww = 0; ww < 4; ++ww) {
        rA += *(f32x4*)(partial + ww * PROW + o0);
        rB += *(f32x4*)(partial + ww * PROW + o1);
    }
    const int uq0 = 510 - 2 * tid;                        // unit of s[2040-tb]
    f32x4 q0  = *(f32x4*)(s_arr + (swz(uq0) << 2));
    f32x4 q1  = *(f32x4*)(s_arr + (swz(uq0 + 1) << 2));
    float e0  = s_arr[swz((uq0 + 2) & 511) << 2];         // s[2048-tb]; tid==0 clamped (dr[0] forced 0)

    float dr[8], pe2[8];
    {
        float term1[8] = { e0, q1[3], q1[2], q1[1], q1[0], q0[3], q0[2], q0[1] };
        float rr[8] = { rA[0],rA[1],rA[2],rA[3], rB[0],rB[1],rB[2],rB[3] };
        float ss[8] = { sA[0],sA[1],sA[2],sA[3], sB[0],sB[1],sB[2],sB[3] };
        #pragma unroll
        for (int e = 0; e < 8; ++e)
            dr[e] = term1[e] + sW - ss[e] - 2.f * rr[e];
        if (tid == 0) dr[0] = 0.f;
        float run = 0.f;
        #pragma unroll
        for (int e = 0; e < 8; ++e) { run += dr[e]; pe2[e] = run; }
    }
    float tsum2 = pe2[7];
    float sc2 = tsum2;
    #pragma unroll
    for (int off = 1; off < 64; off <<= 1) {
        float o = __shfl_up(sc2, off, 64);
        if (lane >= off) sc2 += o;
    }
    // wtot2[w] lives at (row1, phys unit swz(128w+126)): its ONLY part-1 reader is
    // tid 64w+63 (== the writer; swz bijective), and sc2 data-depends on that thread's
    // reduce reads -> ordered, race-free, no extra barrier.
    if (lane == 63) partial[PROW + (swz(128 * w + 126) << 2)] = sc2;
    float thr2 = sc2 - tsum2;
    __syncthreads();

    // ---- scan part 2: normalize -> dbuf ----
    {
        float c0 = partial[PROW + (swz(126) << 2)];
        float c1 = partial[PROW + (swz(254) << 2)];
        float c2 = partial[PROW + (swz(382) << 2)];
        float base = (w > 0 ? c0 : 0.f) + (w > 1 ? c1 : 0.f) + (w > 2 ? c2 : 0.f) + thr2;
        f32x4 dA, dB;
        #pragma unroll
        for (int i = 0; i < 4; ++i) {
            float cumA = base + pe2[i];
            float cumB = base + pe2[4+i];
            dA[i] = (float)(tb + i)     * dr[i]   / (cumA + 1e-7f);
            dB[i] = (float)(tb + 4 + i) * dr[4+i] / (cumB + 1e-7f);
        }
        *(f32x4*)(dbuf + tb)     = dA;
        *(f32x4*)(dbuf + tb + 4) = dB;
    }
    __syncthreads();

    // ---- gather-interpolate ----
    float* op = out + (size_t)blockIdx.x * NOUT;
    if (use_tbl) {
        for (int m = tid; m < NOUT; m += 256) {
            int4 e = tbl[m];
            float wd = __int_as_float(e.z);
            float df = dbuf[e.x], dc = dbuf[e.y];
            op[m] = wd * (dc - df) + df;
        }
    } else {
        for (int m = tid; m < NOUT; m += 256) {
            double midi = 5.0 + (double)m * 0.05;
            float  mf   = (float)midi;
            double lag64 = 22050.0 / (440.0 * exp2(((double)mf - 69.0) / 12.0));
            float  lag  = (float)lag64;
            float  cf = ceilf(lag), ff = floorf(lag);
            float  dc = dbuf[(int)cf], df = dbuf[(int)ff];
            op[m] = (lag - ff) * (dc - df) / (cf - ff) + df;
        }
    }
}

__global__ void table_kernel(int4* __restrict__ tbl) {
    int m = blockIdx.x * 256 + threadIdx.x;
    if (m >= NOUT) return;
    double midi = 5.0 + (double)m * 0.05;            // mirrors np.arange fp64
    float  mf   = (float)midi;                       // .astype(float32)
    double lag64 = 22050.0 / (440.0 * exp2(((double)mf - 69.0) / 12.0));
    float  lag  = (float)lag64;                      // .astype(float32)
    float  cf = ceilf(lag), ff = floorf(lag);
    float  wd = (cf > ff) ? (lag - ff) / (cf - ff) : 0.f;
    int4 e; e.x = (int)ff; e.y = (int)cf; e.z = __float_as_int(wd); e.w = 0;
    tbl[m] = e;
}

extern "C" void kernel_launch(void* const* d_in, const int* in_sizes, int n_in,
                              void* d_out, int out_size, void* d_ws, size_t ws_size,
                              hipStream_t stream) {
    const float* x = (const float*)d_in[0];
    float* out = (float*)d_out;
    int frames = in_sizes[0] / FRAME;   // 16384
    int use_tbl = (ws_size >= (size_t)NOUT * sizeof(int4)) ? 1 : 0;
    int4* tbl = (int4*)d_ws;
    if (use_tbl)
        table_kernel<<<dim3((NOUT + 255) / 256), dim3(256), 0, stream>>>(tbl);
    yingram_kernel<<<dim3(frames), dim3(256), 0, stream>>>(x, out, tbl, use_tbl);
}

// Round 3
// 302.079 us; speedup vs baseline: 1.0763x; 1.0246x over previous
//
#include <hip/hip_runtime.h>
#include <math.h>

typedef __bf16 bf16_t;
typedef __bf16 bf16x8 __attribute__((ext_vector_type(8)));
typedef float  f32x4  __attribute__((ext_vector_type(4)));
typedef float  f32x16 __attribute__((ext_vector_type(16)));
typedef unsigned int u32;
typedef u32 u32x4 __attribute__((ext_vector_type(4)));

#define FRAME 2048
#define NOUT  1580

#define A_STRIDE 2120            // bf16 elements per phase copy (offset 4240B = 16 mod 128: bank-uniform)
#define PROW 2048                // partial row floats (no pad; XOR-swizzled units)
#define B_OFF_BYTES 33920        // arrB directly after arrA (base mod 128 == 0)
#define SARR_OFF_BYTES 32768     // phase-2 s_arr (2048 floats, swizzled) overlays arrA tail + arrB
#define SMEM_BYTES 40960         // == 163840/4 exactly -> 4 blocks/CU (LDS-wise)

#define FIFO_N 12                // A-FIFO depth: 12*4=48 VGPRs; re-read A(12..15) from LDS.
                                 // Keeps total (arch+acc) demand under the 128-reg cap of
                                 // __launch_bounds__(256,4) -> no scratch spill.

// unit-level XOR swizzle: u = float4-unit index within a 2048-float row.
// Spreads stride-128B accesses across all 8 16B slots; bijective on [0,512).
__device__ __forceinline__ int swz(int u) { return u ^ ((u >> 3) & 7); }

__global__ __launch_bounds__(256, 4) void yingram_kernel(
    const float* __restrict__ x, float* __restrict__ out,
    const int4* __restrict__ tbl, int use_tbl)
{
    __shared__ alignas(16) char smem[SMEM_BYTES];
    bf16_t* arrA    = (bf16_t*)smem;                      // [8][A_STRIDE]
    char*   arrBb   = smem + B_OFF_BYTES;                 // phys slots: 16*(B + (B>>3)) bytes, B in [0,384)
    float*  wtot1   = (float*)(smem + B_OFF_BYTES + 128); // arrB pad gap (phys slot 8: B+(B>>3) never == 8)
    float*  partial = (float*)smem;                       // [4][PROW] overlay (phase 2)
    float*  s_arr   = (float*)(smem + SARR_OFF_BYTES);    // [2048] swizzled (phase 2)
    float*  dbuf    = (float*)smem;                       // [2048] overlay on partial row 0 (phase 2b)

    const int tid  = threadIdx.x;
    const int lane = tid & 63;
    const int w    = tid >> 6;
    const int q    = lane >> 5;
    const int col  = lane & 31;
    const float* xp = x + (size_t)blockIdx.x * FRAME;

    // ---- targeted zeroing of never-staged chunks (disjoint from staging: no extra barrier) ----
    if (tid < 64) {
        int sel = tid & 7;
        int c = (sel < 3) ? sel : sel + 257;              // {0,1,2,260..264}
        u32x4 z = {0u,0u,0u,0u};
        *(u32x4*)(arrA + (tid >> 3) * A_STRIDE + 8 * c) = z;
    } else if (tid < 191) {
        int B = tid + 193;                                // logical chunks 257..383
        u32x4 z = {0u,0u,0u,0u};
        *(u32x4*)(arrBb + 16 * (B + (B >> 3))) = z;
    }

    // ---- window load: xt[8tid-8 .. 8tid+7] ----
    f32x4 f0 = {0,0,0,0}, f1 = {0,0,0,0}, f2, f3;
    const f32x4* xv4 = (const f32x4*)(xp + 8 * tid - 8);
    if (tid != 0) { f0 = xv4[0]; f1 = xv4[1]; }
    f2 = xv4[2]; f3 = xv4[3];

    float xf[16];
    #pragma unroll
    for (int i = 0; i < 4; ++i) {
        xf[i] = f0[i]; xf[4+i] = f1[i]; xf[8+i] = f2[i]; xf[12+i] = f3[i];
    }
    // pack to bf16 dwords: W[j] = xb[2j] | xb[2j+1]<<16
    u32 W[8];
    #pragma unroll
    for (int j = 0; j < 8; ++j) {
        union { bf16_t h[2]; u32 u; } cv;
        cv.h[0] = (bf16_t)xf[2*j];
        cv.h[1] = (bf16_t)xf[2*j+1];
        W[j] = cv.u;
    }

    // ---- staging: 8 phase copies (A) + padded B copy, all b128 writes ----
    u32x4 D7;
    #pragma unroll
    for (int p = 0; p < 8; ++p) {
        int a = p >> 1;
        u32x4 D;
        if ((p & 1) == 0) {
            D[0] = W[a]; D[1] = W[a+1]; D[2] = W[a+2]; D[3] = W[a+3];
        } else {
            #pragma unroll
            for (int i = 0; i < 4; ++i)
                D[i] = (W[a+i] >> 16) | (W[a+i+1] << 16);
        }
        *(u32x4*)(arrA + p * A_STRIDE + 8 * (tid + 3)) = D;
        if (p == 7) D7 = D;
    }
    *(u32x4*)(arrBb + 16 * (tid + (tid >> 3))) = D7;      // logical chunk tid = window[7..14]

    if (tid == 255) {
        // A chunk 259 (tail): elements xb[8+p+j], zero beyond window
        #pragma unroll
        for (int p = 0; p < 8; ++p) {
            int a = p >> 1;
            u32x4 D;
            #pragma unroll
            for (int i = 0; i < 4; ++i) {
                int lo = 4 + a + i;
                if ((p & 1) == 0) {
                    D[i] = (lo <= 7) ? W[lo] : 0u;
                } else {
                    u32 x0 = (lo <= 7) ? (W[lo] >> 16) : 0u;
                    u32 x1 = (lo + 1 <= 7) ? (W[lo+1] << 16) : 0u;
                    D[i] = x0 | x1;
                }
            }
            *(u32x4*)(arrA + p * A_STRIDE + 8 * 259) = D;
        }
        u32x4 Db = { W[7] >> 16, 0u, 0u, 0u };            // B chunk 256 = [x2047, 0..]
        *(u32x4*)(arrBb + 16 * (256 + (256 >> 3))) = Db;
    }

    // ---- energy scan part 1 (own elements = xf[8..15]) ----
    float sq[8], pe[8];
    {
        float run = 0.f;
        #pragma unroll
        for (int e = 0; e < 8; ++e) {
            float v = xf[8 + e];
            sq[e] = v * v; run += sq[e]; pe[e] = run;
        }
    }
    float tsum = pe[7];
    float sc = tsum;
    #pragma unroll
    for (int off = 1; off < 64; off <<= 1) {
        float o = __shfl_up(sc, off, 64);
        if (lane >= off) sc += o;
    }
    if (lane == 63) wtot1[w] = sc;
    float thr_off = sc - tsum;

    __syncthreads();   // staging + wtot1 complete

    // ---- energy scan part 2: exclusive prefix kept in REGISTERS (written to LDS after K-loop) ----
    f32x4 sA, sB;
    float sW;
    {
        float b0 = wtot1[0], b1 = wtot1[1], b2 = wtot1[2], b3 = wtot1[3];
        float base = (w > 0 ? b0 : 0.f) + (w > 1 ? b1 : 0.f) + (w > 2 ? b2 : 0.f) + thr_off;
        sW = b0 + b1 + b2 + b3;                           // total energy s[2048]
        #pragma unroll
        for (int i = 0; i < 4; ++i) {
            sA[i] = base + pe[i]   - sq[i];
            sB[i] = base + pe[4+i] - sq[4+i];
        }
    }

    // ---- MFMA K-loop: A-fragment register FIFO (depth 12) removes the b1 re-read for
    //      most dual iterations; A(12..15) re-read from LDS (conflict-free pattern). ----
    const bf16_t* aPtr = arrA + (col & 7) * A_STRIDE + (col & ~7) + 8 * q + 16 * w;
    const bf16_t* aBase = aPtr;                           // A(0)
    int B0 = 2 * w + q + 4 * col;
    const bf16_t* bPtr = (const bf16_t*)arrBb + 8 * (B0 + (B0 >> 3));
    f32x16 acc0, acc1;
    #pragma unroll
    for (int v = 0; v < 16; ++v) { acc0[v] = 0.f; acc1[v] = 0.f; }

    bf16x8 fifo[FIFO_N];
    #pragma unroll
    for (int i = 0; i < 16; ++i) {                        // global i = 0..15: fill FIFO
        bf16x8 av = *(const bf16x8*)aPtr;
        bf16x8 bv = *(const bf16x8*)bPtr;
        __builtin_amdgcn_s_setprio(1);
        acc0 = __builtin_amdgcn_mfma_f32_32x32x16_bf16(av, bv, acc0, 0, 0, 0);
        __builtin_amdgcn_s_setprio(0);
        if (i < FIFO_N) fifo[i] = av;
        aPtr += 64; bPtr += 72;
    }
    #pragma unroll
    for (int i = 0; i < 16; ++i) {                        // global i = 16..31: dual
        bf16x8 av = *(const bf16x8*)aPtr;
        bf16x8 bv = *(const bf16x8*)bPtr;
        bf16x8 ai;
        if (i < FIFO_N) ai = fifo[i];
        else            ai = *(const bf16x8*)(aBase + 64 * i);   // re-read A(i), i=12..15
        __builtin_amdgcn_s_setprio(1);
        acc0 = __builtin_amdgcn_mfma_f32_32x32x16_bf16(av, bv, acc0, 0, 0, 0);
        acc1 = __builtin_amdgcn_mfma_f32_32x32x16_bf16(ai, bv, acc1, 0, 0, 0);
        __builtin_amdgcn_s_setprio(0);
        if (i == 0) fifo[0] = av;                         // fifo[0] <- A(16) for the w==0 tail
        aPtr += 64; bPtr += 72;
    }
    if (w < 2) {                                          // global i = 32 (k = 128/129)
        bf16x8 av = *(const bf16x8*)aPtr;
        bf16x8 bv = *(const bf16x8*)bPtr;
        __builtin_amdgcn_s_setprio(1);
        acc0 = __builtin_amdgcn_mfma_f32_32x32x16_bf16(av, bv, acc0, 0, 0, 0);
        if (w == 0)
            acc1 = __builtin_amdgcn_mfma_f32_32x32x16_bf16(fifo[0], bv, acc1, 0, 0, 0);
        __builtin_amdgcn_s_setprio(0);
    }

    __syncthreads();   // all waves done reading arrA/arrB

    // ---- partial + s_arr writes: swizzled float4 units (reg j=3..0 -> descending lags) ----
    float* prow = partial + w * PROW;
    #pragma unroll
    for (int g = 0; g < 4; ++g) {
        int L0 = 28 + 32 * col - 8 * g - 4 * q;
        f32x4 v0 = { acc0[4*g+3], acc0[4*g+2], acc0[4*g+1], acc0[4*g] };
        *(f32x4*)(prow + (swz(L0 >> 2) << 2)) = v0;
        int L1 = L0 + 1024;
        f32x4 v1 = { acc1[4*g+3], acc1[4*g+2], acc1[4*g+1], acc1[4*g] };
        *(f32x4*)(prow + (swz(L1 >> 2) << 2)) = v1;
    }
    *(f32x4*)(s_arr + (swz(2 * tid) << 2))     = sA;      // s[8tid..8tid+3]
    *(f32x4*)(s_arr + (swz(2 * tid + 1) << 2)) = sB;      // s[8tid+4..8tid+7]
    __syncthreads();

    // ---- reduce partials, d_raw, scan part 1 ----
    const int tb = 8 * tid;
    const int o0 = swz(2 * tid) << 2;
    const int o1 = swz(2 * tid + 1) << 2;
    f32x4 rA = {0,0,0,0}, rB = {0,0,0,0};
    #pragma unroll
    for (int ww = 0; ww < 4; ++ww) {
        rA += *(f32x4*)(partial + ww * PROW + o0);
        rB += *(f32x4*)(partial + ww * PROW + o1);
    }
    const int uq0 = 510 - 2 * tid;                        // unit of s[2040-tb]
    f32x4 q0  = *(f32x4*)(s_arr + (swz(uq0) << 2));
    f32x4 q1  = *(f32x4*)(s_arr + (swz(uq0 + 1) << 2));
    float e0  = s_arr[swz((uq0 + 2) & 511) << 2];         // s[2048-tb]; tid==0 clamped (dr[0] forced 0)

    float dr[8], pe2[8];
    {
        float term1[8] = { e0, q1[3], q1[2], q1[1], q1[0], q0[3], q0[2], q0[1] };
        float rr[8] = { rA[0],rA[1],rA[2],rA[3], rB[0],rB[1],rB[2],rB[3] };
        float ss[8] = { sA[0],sA[1],sA[2],sA[3], sB[0],sB[1],sB[2],sB[3] };
        #pragma unroll
        for (int e = 0; e < 8; ++e)
            dr[e] = term1[e] + sW - ss[e] - 2.f * rr[e];
        if (tid == 0) dr[0] = 0.f;
        float run = 0.f;
        #pragma unroll
        for (int e = 0; e < 8; ++e) { run += dr[e]; pe2[e] = run; }
    }
    float tsum2 = pe2[7];
    float sc2 = tsum2;
    #pragma unroll
    for (int off = 1; off < 64; off <<= 1) {
        float o = __shfl_up(sc2, off, 64);
        if (lane >= off) sc2 += o;
    }
    // wtot2[w] lives at (row1, phys unit swz(128w+126)): its ONLY part-1 reader is
    // tid 64w+63 (== the writer; swz bijective), and sc2 data-depends on that thread's
    // reduce reads -> ordered, race-free, no extra barrier.
    if (lane == 63) partial[PROW + (swz(128 * w + 126) << 2)] = sc2;
    float thr2 = sc2 - tsum2;
    __syncthreads();

    // ---- scan part 2: normalize -> dbuf ----
    {
        float c0 = partial[PROW + (swz(126) << 2)];
        float c1 = partial[PROW + (swz(254) << 2)];
        float c2 = partial[PROW + (swz(382) << 2)];
        float base = (w > 0 ? c0 : 0.f) + (w > 1 ? c1 : 0.f) + (w > 2 ? c2 : 0.f) + thr2;
        f32x4 dA, dB;
        #pragma unroll
        for (int i = 0; i < 4; ++i) {
            float cumA = base + pe2[i];
            float cumB = base + pe2[4+i];
            dA[i] = (float)(tb + i)     * dr[i]   / (cumA + 1e-7f);
            dB[i] = (float)(tb + 4 + i) * dr[4+i] / (cumB + 1e-7f);
        }
        *(f32x4*)(dbuf + tb)     = dA;
        *(f32x4*)(dbuf + tb + 4) = dB;
    }
    __syncthreads();

    // ---- gather-interpolate ----
    float* op = out + (size_t)blockIdx.x * NOUT;
    if (use_tbl) {
        for (int m = tid; m < NOUT; m += 256) {
            int4 e = tbl[m];
            float wd = __int_as_float(e.z);
            float df = dbuf[e.x], dc = dbuf[e.y];
            op[m] = wd * (dc - df) + df;
        }
    } else {
        for (int m = tid; m < NOUT; m += 256) {
            double midi = 5.0 + (double)m * 0.05;
            float  mf   = (float)midi;
            double lag64 = 22050.0 / (440.0 * exp2(((double)mf - 69.0) / 12.0));
            float  lag  = (float)lag64;
            float  cf = ceilf(lag), ff = floorf(lag);
            float  dc = dbuf[(int)cf], df = dbuf[(int)ff];
            op[m] = (lag - ff) * (dc - df) / (cf - ff) + df;
        }
    }
}

__global__ void table_kernel(int4* __restrict__ tbl) {
    int m = blockIdx.x * 256 + threadIdx.x;
    if (m >= NOUT) return;
    double midi = 5.0 + (double)m * 0.05;            // mirrors np.arange fp64
    float  mf   = (float)midi;                       // .astype(float32)
    double lag64 = 22050.0 / (440.0 * exp2(((double)mf - 69.0) / 12.0));
    float  lag  = (float)lag64;                      // .astype(float32)
    float  cf = ceilf(lag), ff = floorf(lag);
    float  wd = (cf > ff) ? (lag - ff) / (cf - ff) : 0.f;
    int4 e; e.x = (int)ff; e.y = (int)cf; e.z = __float_as_int(wd); e.w = 0;
    tbl[m] = e;
}

extern "C" void kernel_launch(void* const* d_in, const int* in_sizes, int n_in,
                              void* d_out, int out_size, void* d_ws, size_t ws_size,
                              hipStream_t stream) {
    const float* x = (const float*)d_in[0];
    float* out = (float*)d_out;
    int frames = in_sizes[0] / FRAME;   // 16384
    int use_tbl = (ws_size >= (size_t)NOUT * sizeof(int4)) ? 1 : 0;
    int4* tbl = (int4*)d_ws;
    if (use_tbl)
        table_kernel<<<dim3((NOUT + 255) / 256), dim3(256), 0, stream>>>(tbl);
    yingram_kernel<<<dim3(frames), dim3(256), 0, stream>>>(x, out, tbl, use_tbl);
}

// Round 4
// 294.232 us; speedup vs baseline: 1.1050x; 1.0267x over previous
//
#include <hip/hip_runtime.h>
#include <math.h>

typedef __bf16 bf16_t;
typedef __bf16 bf16x8 __attribute__((ext_vector_type(8)));
typedef float  f32x4  __attribute__((ext_vector_type(4)));
typedef float  f32x16 __attribute__((ext_vector_type(16)));
typedef unsigned int u32;
typedef u32 u32x4 __attribute__((ext_vector_type(4)));

#define FRAME 2048
#define NOUT  1580

#define A_STRIDE 2120            // bf16 elements per phase copy (offset 4240B = 16 mod 128: bank-uniform)
#define PROW 2048                // partial row floats (no pad; XOR-swizzled units)
#define B_OFF_BYTES 33920        // arrB directly after arrA (base mod 128 == 0)
#define SARR_OFF_BYTES 32768     // phase-2 s_arr (2048 floats, swizzled) overlays arrA tail + arrB
#define SMEM_BYTES 40960         // == 163840/4 exactly -> 4 blocks/CU (LDS-wise)

#define FIFO_N 12                // A-FIFO depth: keeps (arch+acc) reg demand under the 128 cap -> no spill

// unit-level XOR swizzle: u = float4-unit index within a 2048-float row.
// Spreads stride-128B accesses across all 8 16B slots; bijective on [0,512).
__device__ __forceinline__ int swz(int u) { return u ^ ((u >> 3) & 7); }

// swizzled scalar index for a float array laid out in swz'd f32x4 units
__device__ __forceinline__ int swzi(int idx) { return (swz(idx >> 2) << 2) | (idx & 3); }

// 64-lane inclusive add-scan via DPP (classic GCN sequence) — no LDS traffic.
// row_shr:1/2/4/8 within 16-lane rows, then row_bcast:15 (rows 1,3) and
// row_bcast:31 (rows 2,3) carry the row prefixes. bound_ctrl=1 -> invalid reads 0.
__device__ __forceinline__ float wave_incl_scan(float x) {
    union { float f; int i; } c, t;
    c.f = x;
#define DPP_ADD(ctrl, rmask) \
    { t.i = __builtin_amdgcn_update_dpp(0, c.i, ctrl, rmask, 0xf, true); c.f += t.f; }
    DPP_ADD(0x111, 0xf);   // row_shr:1
    DPP_ADD(0x112, 0xf);   // row_shr:2
    DPP_ADD(0x114, 0xf);   // row_shr:4
    DPP_ADD(0x118, 0xf);   // row_shr:8
    DPP_ADD(0x142, 0xa);   // row_bcast:15 -> rows 1,3
    DPP_ADD(0x143, 0xc);   // row_bcast:31 -> rows 2,3
#undef DPP_ADD
    return c.f;
}

__global__ __launch_bounds__(256, 4) void yingram_kernel(
    const float* __restrict__ x, float* __restrict__ out,
    const int4* __restrict__ tbl, int use_tbl)
{
    __shared__ alignas(16) char smem[SMEM_BYTES];
    bf16_t* arrA    = (bf16_t*)smem;                      // [8][A_STRIDE]
    char*   arrBb   = smem + B_OFF_BYTES;                 // phys slots: 16*(B + (B>>3)) bytes, B in [0,384)
    float*  wtot1   = (float*)(smem + B_OFF_BYTES + 128); // arrB pad gap (phys slot 8: B+(B>>3) never == 8)
    float*  partial = (float*)smem;                       // [4][PROW] overlay (phase 2)
    float*  s_arr   = (float*)(smem + SARR_OFF_BYTES);    // [2048] swizzled (phase 2)
    float*  dbuf    = (float*)smem;                       // [2048] swizzled, overlay on partial row 0

    const int tid  = threadIdx.x;
    const int lane = tid & 63;
    const int w    = tid >> 6;
    const int q    = lane >> 5;
    const int col  = lane & 31;
    const float* xp = x + (size_t)blockIdx.x * FRAME;

    // ---- targeted zeroing of never-staged chunks (disjoint from staging: no extra barrier) ----
    if (tid < 64) {
        int sel = tid & 7;
        int c = (sel < 3) ? sel : sel + 257;              // {0,1,2,260..264}
        u32x4 z = {0u,0u,0u,0u};
        *(u32x4*)(arrA + (tid >> 3) * A_STRIDE + 8 * c) = z;
    } else if (tid < 191) {
        int B = tid + 193;                                // logical chunks 257..383
        u32x4 z = {0u,0u,0u,0u};
        *(u32x4*)(arrBb + 16 * (B + (B >> 3))) = z;
    }

    // ---- window load: xt[8tid-8 .. 8tid+7] ----
    f32x4 f0 = {0,0,0,0}, f1 = {0,0,0,0}, f2, f3;
    const f32x4* xv4 = (const f32x4*)(xp + 8 * tid - 8);
    if (tid != 0) { f0 = xv4[0]; f1 = xv4[1]; }
    f2 = xv4[2]; f3 = xv4[3];

    float xf[16];
    #pragma unroll
    for (int i = 0; i < 4; ++i) {
        xf[i] = f0[i]; xf[4+i] = f1[i]; xf[8+i] = f2[i]; xf[12+i] = f3[i];
    }
    // pack to bf16 dwords: W[j] = xb[2j] | xb[2j+1]<<16
    u32 W[8];
    #pragma unroll
    for (int j = 0; j < 8; ++j) {
        union { bf16_t h[2]; u32 u; } cv;
        cv.h[0] = (bf16_t)xf[2*j];
        cv.h[1] = (bf16_t)xf[2*j+1];
        W[j] = cv.u;
    }

    // ---- staging: 8 phase copies (A) + padded B copy, all b128 writes ----
    u32x4 D7;
    #pragma unroll
    for (int p = 0; p < 8; ++p) {
        int a = p >> 1;
        u32x4 D;
        if ((p & 1) == 0) {
            D[0] = W[a]; D[1] = W[a+1]; D[2] = W[a+2]; D[3] = W[a+3];
        } else {
            #pragma unroll
            for (int i = 0; i < 4; ++i)
                D[i] = (W[a+i] >> 16) | (W[a+i+1] << 16);
        }
        *(u32x4*)(arrA + p * A_STRIDE + 8 * (tid + 3)) = D;
        if (p == 7) D7 = D;
    }
    *(u32x4*)(arrBb + 16 * (tid + (tid >> 3))) = D7;      // logical chunk tid = window[7..14]

    if (tid == 255) {
        // A chunk 259 (tail): elements xb[8+p+j], zero beyond window
        #pragma unroll
        for (int p = 0; p < 8; ++p) {
            int a = p >> 1;
            u32x4 D;
            #pragma unroll
            for (int i = 0; i < 4; ++i) {
                int lo = 4 + a + i;
                if ((p & 1) == 0) {
                    D[i] = (lo <= 7) ? W[lo] : 0u;
                } else {
                    u32 x0 = (lo <= 7) ? (W[lo] >> 16) : 0u;
                    u32 x1 = (lo + 1 <= 7) ? (W[lo+1] << 16) : 0u;
                    D[i] = x0 | x1;
                }
            }
            *(u32x4*)(arrA + p * A_STRIDE + 8 * 259) = D;
        }
        u32x4 Db = { W[7] >> 16, 0u, 0u, 0u };            // B chunk 256 = [x2047, 0..]
        *(u32x4*)(arrBb + 16 * (256 + (256 >> 3))) = Db;
    }

    // ---- energy scan part 1 (own elements = xf[8..15]) ----
    float sq[8], pe[8];
    {
        float run = 0.f;
        #pragma unroll
        for (int e = 0; e < 8; ++e) {
            float v = xf[8 + e];
            sq[e] = v * v; run += sq[e]; pe[e] = run;
        }
    }
    float tsum = pe[7];
    float sc = wave_incl_scan(tsum);                      // DPP: no LDS traffic
    if (lane == 63) wtot1[w] = sc;
    float thr_off = sc - tsum;

    __syncthreads();   // staging + wtot1 complete

    // ---- energy scan part 2: exclusive prefix kept in REGISTERS (written to LDS after K-loop) ----
    f32x4 sA, sB;
    float sW;
    {
        float b0 = wtot1[0], b1 = wtot1[1], b2 = wtot1[2], b3 = wtot1[3];
        float base = (w > 0 ? b0 : 0.f) + (w > 1 ? b1 : 0.f) + (w > 2 ? b2 : 0.f) + thr_off;
        sW = b0 + b1 + b2 + b3;                           // total energy s[2048]
        #pragma unroll
        for (int i = 0; i < 4; ++i) {
            sA[i] = base + pe[i]   - sq[i];
            sB[i] = base + pe[4+i] - sq[4+i];
        }
    }

    // ---- MFMA K-loop: A-fragment register FIFO (depth 12) removes the b1 re-read for
    //      most dual iterations; A(12..15) re-read from LDS (conflict-free pattern). ----
    const bf16_t* aPtr = arrA + (col & 7) * A_STRIDE + (col & ~7) + 8 * q + 16 * w;
    const bf16_t* aBase = aPtr;                           // A(0)
    int B0 = 2 * w + q + 4 * col;
    const bf16_t* bPtr = (const bf16_t*)arrBb + 8 * (B0 + (B0 >> 3));
    f32x16 acc0, acc1;
    #pragma unroll
    for (int v = 0; v < 16; ++v) { acc0[v] = 0.f; acc1[v] = 0.f; }

    bf16x8 fifo[FIFO_N];
    #pragma unroll
    for (int i = 0; i < 16; ++i) {                        // global i = 0..15: fill FIFO
        bf16x8 av = *(const bf16x8*)aPtr;
        bf16x8 bv = *(const bf16x8*)bPtr;
        __builtin_amdgcn_s_setprio(1);
        acc0 = __builtin_amdgcn_mfma_f32_32x32x16_bf16(av, bv, acc0, 0, 0, 0);
        __builtin_amdgcn_s_setprio(0);
        if (i < FIFO_N) fifo[i] = av;
        aPtr += 64; bPtr += 72;
    }
    #pragma unroll
    for (int i = 0; i < 16; ++i) {                        // global i = 16..31: dual
        bf16x8 av = *(const bf16x8*)aPtr;
        bf16x8 bv = *(const bf16x8*)bPtr;
        bf16x8 ai;
        if (i < FIFO_N) ai = fifo[i];
        else            ai = *(const bf16x8*)(aBase + 64 * i);   // re-read A(i), i=12..15
        __builtin_amdgcn_s_setprio(1);
        acc0 = __builtin_amdgcn_mfma_f32_32x32x16_bf16(av, bv, acc0, 0, 0, 0);
        acc1 = __builtin_amdgcn_mfma_f32_32x32x16_bf16(ai, bv, acc1, 0, 0, 0);
        __builtin_amdgcn_s_setprio(0);
        if (i == 0) fifo[0] = av;                         // fifo[0] <- A(16) for the w==0 tail
        aPtr += 64; bPtr += 72;
    }
    if (w < 2) {                                          // global i = 32 (k = 128/129)
        bf16x8 av = *(const bf16x8*)aPtr;
        bf16x8 bv = *(const bf16x8*)bPtr;
        __builtin_amdgcn_s_setprio(1);
        acc0 = __builtin_amdgcn_mfma_f32_32x32x16_bf16(av, bv, acc0, 0, 0, 0);
        if (w == 0)
            acc1 = __builtin_amdgcn_mfma_f32_32x32x16_bf16(fifo[0], bv, acc1, 0, 0, 0);
        __builtin_amdgcn_s_setprio(0);
    }

    __syncthreads();   // all waves done reading arrA/arrB

    // ---- partial + s_arr writes: swizzled float4 units (reg j=3..0 -> descending lags) ----
    float* prow = partial + w * PROW;
    #pragma unroll
    for (int g = 0; g < 4; ++g) {
        int L0 = 28 + 32 * col - 8 * g - 4 * q;
        f32x4 v0 = { acc0[4*g+3], acc0[4*g+2], acc0[4*g+1], acc0[4*g] };
        *(f32x4*)(prow + (swz(L0 >> 2) << 2)) = v0;
        int L1 = L0 + 1024;
        f32x4 v1 = { acc1[4*g+3], acc1[4*g+2], acc1[4*g+1], acc1[4*g] };
        *(f32x4*)(prow + (swz(L1 >> 2) << 2)) = v1;
    }
    *(f32x4*)(s_arr + (swz(2 * tid) << 2))     = sA;      // s[8tid..8tid+3]
    *(f32x4*)(s_arr + (swz(2 * tid + 1) << 2)) = sB;      // s[8tid+4..8tid+7]
    __syncthreads();

    // ---- reduce partials, d_raw, scan part 1 ----
    const int tb = 8 * tid;
    const int o0 = swz(2 * tid) << 2;
    const int o1 = swz(2 * tid + 1) << 2;
    f32x4 rA = {0,0,0,0}, rB = {0,0,0,0};
    #pragma unroll
    for (int ww = 0; ww < 4; ++ww) {
        rA += *(f32x4*)(partial + ww * PROW + o0);
        rB += *(f32x4*)(partial + ww * PROW + o1);
    }
    const int uq0 = 510 - 2 * tid;                        // unit of s[2040-tb]
    f32x4 q0  = *(f32x4*)(s_arr + (swz(uq0) << 2));
    f32x4 q1  = *(f32x4*)(s_arr + (swz(uq0 + 1) << 2));
    float e0  = s_arr[swz((uq0 + 2) & 511) << 2];         // s[2048-tb]; tid==0 clamped (dr[0] forced 0)

    float dr[8], pe2[8];
    {
        float term1[8] = { e0, q1[3], q1[2], q1[1], q1[0], q0[3], q0[2], q0[1] };
        float rr[8] = { rA[0],rA[1],rA[2],rA[3], rB[0],rB[1],rB[2],rB[3] };
        float ss[8] = { sA[0],sA[1],sA[2],sA[3], sB[0],sB[1],sB[2],sB[3] };
        #pragma unroll
        for (int e = 0; e < 8; ++e)
            dr[e] = term1[e] + sW - ss[e] - 2.f * rr[e];
        if (tid == 0) dr[0] = 0.f;
        float run = 0.f;
        #pragma unroll
        for (int e = 0; e < 8; ++e) { run += dr[e]; pe2[e] = run; }
    }
    float tsum2 = pe2[7];
    float sc2 = wave_incl_scan(tsum2);                    // DPP: no LDS traffic
    // wtot2[w] lives at (row1, phys unit swz(128w+126)): its ONLY part-1 reader is
    // tid 64w+63 (== the writer; swz bijective), and sc2 data-depends on that thread's
    // reduce reads -> ordered, race-free, no extra barrier.
    if (lane == 63) partial[PROW + (swz(128 * w + 126) << 2)] = sc2;
    float thr2 = sc2 - tsum2;
    __syncthreads();

    // ---- scan part 2: normalize -> dbuf (swizzled layout; gather uses pre-swizzled idx) ----
    {
        float c0 = partial[PROW + (swz(126) << 2)];
        float c1 = partial[PROW + (swz(254) << 2)];
        float c2 = partial[PROW + (swz(382) << 2)];
        float base = (w > 0 ? c0 : 0.f) + (w > 1 ? c1 : 0.f) + (w > 2 ? c2 : 0.f) + thr2;
        f32x4 dA, dB;
        #pragma unroll
        for (int i = 0; i < 4; ++i) {
            float cumA = base + pe2[i];
            float cumB = base + pe2[4+i];
            dA[i] = (float)(tb + i)     * dr[i]   / (cumA + 1e-7f);
            dB[i] = (float)(tb + 4 + i) * dr[4+i] / (cumB + 1e-7f);
        }
        *(f32x4*)(dbuf + (swz(2 * tid) << 2))     = dA;
        *(f32x4*)(dbuf + (swz(2 * tid + 1) << 2)) = dB;
    }
    __syncthreads();

    // ---- gather-interpolate (indices pre-swizzled) ----
    float* op = out + (size_t)blockIdx.x * NOUT;
    if (use_tbl) {
        for (int m = tid; m < NOUT; m += 256) {
            int4 e = tbl[m];
            float wd = __int_as_float(e.z);
            float df = dbuf[e.x], dc = dbuf[e.y];
            op[m] = wd * (dc - df) + df;
        }
    } else {
        for (int m = tid; m < NOUT; m += 256) {
            double midi = 5.0 + (double)m * 0.05;
            float  mf   = (float)midi;
            double lag64 = 22050.0 / (440.0 * exp2(((double)mf - 69.0) / 12.0));
            float  lag  = (float)lag64;
            float  cf = ceilf(lag), ff = floorf(lag);
            float  dc = dbuf[swzi((int)cf)], df = dbuf[swzi((int)ff)];
            op[m] = (lag - ff) * (dc - df) / (cf - ff) + df;
        }
    }
}

__global__ void table_kernel(int4* __restrict__ tbl) {
    int m = blockIdx.x * 256 + threadIdx.x;
    if (m >= NOUT) return;
    double midi = 5.0 + (double)m * 0.05;            // mirrors np.arange fp64
    float  mf   = (float)midi;                       // .astype(float32)
    double lag64 = 22050.0 / (440.0 * exp2(((double)mf - 69.0) / 12.0));
    float  lag  = (float)lag64;                      // .astype(float32)
    float  cf = ceilf(lag), ff = floorf(lag);
    float  wd = (cf > ff) ? (lag - ff) / (cf - ff) : 0.f;
    int fi = (int)ff, ci = (int)cf;
    // store PRE-SWIZZLED indices into the swizzled dbuf layout
    int fs = ((fi >> 2) ^ ((fi >> 5) & 7)) * 4 + (fi & 3);
    int cs = ((ci >> 2) ^ ((ci >> 5) & 7)) * 4 + (ci & 3);
    int4 e; e.x = fs; e.y = cs; e.z = __float_as_int(wd); e.w = 0;
    tbl[m] = e;
}

extern "C" void kernel_launch(void* const* d_in, const int* in_sizes, int n_in,
                              void* d_out, int out_size, void* d_ws, size_t ws_size,
                              hipStream_t stream) {
    const float* x = (const float*)d_in[0];
    float* out = (float*)d_out;
    int frames = in_sizes[0] / FRAME;   // 16384
    int use_tbl = (ws_size >= (size_t)NOUT * sizeof(int4)) ? 1 : 0;
    int4* tbl = (int4*)d_ws;
    if (use_tbl)
        table_kernel<<<dim3((NOUT + 255) / 256), dim3(256), 0, stream>>>(tbl);
    yingram_kernel<<<dim3(frames), dim3(256), 0, stream>>>(x, out, tbl, use_tbl);
}